// Round 1
// baseline (705.439 us; speedup 1.0000x reference)
//
#include <hip/hip_runtime.h>
#include <hip/hip_bf16.h>

#define DD 128
#define KK 256
#define TS 256        // samples per stage-3 tile
#define ROWB 136      // padded LDS row stride (bf16 elems) — 68 dwords -> 8 lanes/16B-slot, balanced for ds_read_b128
#define SPB1 1024     // samples per stage-1 block

typedef __attribute__((ext_vector_type(8))) short short8;
typedef __attribute__((ext_vector_type(4))) float f32x4;

static __device__ __forceinline__ unsigned short f2bf(float f) {
    unsigned int u = __float_as_uint(f);
    return (unsigned short)((u + 0x7fffu + ((u >> 16) & 1u)) >> 16);   // RNE
}
static __device__ __forceinline__ float bf2f(unsigned short h) {
    return __uint_as_float(((unsigned int)h) << 16);
}

// ---------------- stage 1: counting-sort gather, 8-deep load pipeline ----------------
// MODE 0: per-block partial slot.  MODE 2: global-atomic merge (tiny-ws fallback).
template<int MODE>
__global__ __launch_bounds__(1024) void k_stage1_gather(
    const float* __restrict__ X, const int* __restrict__ labels,
    float* __restrict__ partial)
{
    __shared__ int lab[SPB1];
    __shared__ int idx[SPB1];
    __shared__ int hist[KK];
    __shared__ int start[KK + 1];
    __shared__ int cursor[KK];

    const int tid  = threadIdx.x;
    const int lane = tid & 63;
    const int wave = tid >> 6;
    const int base = blockIdx.x * SPB1;

    if (tid < KK) hist[tid] = 0;
    __syncthreads();
    {
        const int l = labels[base + tid];
        lab[tid] = l;
        atomicAdd(&hist[l], 1);
    }
    __syncthreads();
    if (wave == 0) {                        // exclusive scan of 256 bins in one wave
        const int h0 = hist[4*lane], h1 = hist[4*lane+1];
        const int h2 = hist[4*lane+2], h3 = hist[4*lane+3];
        const int s = h0 + h1 + h2 + h3;
        int t = s;
#pragma unroll
        for (int d = 1; d < 64; d <<= 1) { const int u = __shfl_up(t, d); if (lane >= d) t += u; }
        const int e = t - s;
        start[4*lane]   = e;
        start[4*lane+1] = e + h0;
        start[4*lane+2] = e + h0 + h1;
        start[4*lane+3] = e + h0 + h1 + h2;
        if (lane == 63) start[KK] = t;
    }
    __syncthreads();
    if (tid < KK) cursor[tid] = start[tid];
    __syncthreads();
    {
        const int pos = atomicAdd(&cursor[lab[tid]], 1);
        idx[pos] = tid;
    }
    __syncthreads();

    // wave w owns contiguous clusters [16w, 16w+16); flat member walk, 8 loads in flight
    const int c1 = (wave << 4) + 16;
    int c = wave << 4;
    const int s0 = start[c], s1 = start[c1];
    const int cnt = s1 - s0;
    int nx = start[c + 1];                  // register-cached cluster boundary (was LDS read per row)

    float2 pf[8];
#pragma unroll
    for (int j = 0; j < 8; ++j)
        if (j < cnt)
            pf[j] = *(const float2*)(X + (size_t)(base + idx[s0 + j]) * DD + 2 * lane);

    float2 acc = make_float2(0.f, 0.f);
    int i = 0;
    for (; i + 8 <= cnt; i += 8) {
#pragma unroll
        for (int j = 0; j < 8; ++j) {
            const float2 v = pf[j];
            if (i + j + 8 < cnt)
                pf[j] = *(const float2*)(X + (size_t)(base + idx[s0 + i + j + 8]) * DD + 2 * lane);
            while (s0 + i + j >= nx) {       // wave-uniform boundary flush
                if (MODE == 2) {
                    atomicAdd(&partial[(size_t)c * DD + 2*lane],     acc.x);
                    atomicAdd(&partial[(size_t)c * DD + 2*lane + 1], acc.y);
                } else {
                    *(float2*)(partial + ((size_t)blockIdx.x * KK + c) * DD + 2*lane) = acc;
                }
                acc = make_float2(0.f, 0.f); ++c; nx = start[c + 1];
            }
            acc.x += v.x; acc.y += v.y;
        }
    }
#pragma unroll
    for (int j = 0; j < 8; ++j) {                       // tail (<8 rows), pf[j] = row i+j
        if (i + j < cnt) {
            const float2 v = pf[j];
            while (s0 + i + j >= nx) {
                if (MODE == 2) {
                    atomicAdd(&partial[(size_t)c * DD + 2*lane],     acc.x);
                    atomicAdd(&partial[(size_t)c * DD + 2*lane + 1], acc.y);
                } else {
                    *(float2*)(partial + ((size_t)blockIdx.x * KK + c) * DD + 2*lane) = acc;
                }
                acc = make_float2(0.f, 0.f); ++c; nx = start[c + 1];
            }
            acc.x += v.x; acc.y += v.y;
        }
    }
    while (c < c1) {                                    // flush trailing (incl. empty) clusters
        if (MODE == 2) {
            atomicAdd(&partial[(size_t)c * DD + 2*lane],     acc.x);
            atomicAdd(&partial[(size_t)c * DD + 2*lane + 1], acc.y);
        } else {
            *(float2*)(partial + ((size_t)blockIdx.x * KK + c) * DD + 2*lane) = acc;
        }
        acc = make_float2(0.f, 0.f); ++c;
    }
}

// ---------------- stage 2: reduce partials, normalize (counts cancel), emit bf16 ----------------
__global__ void k_stage2(const float* __restrict__ partial, int nparts,
                         unsigned short* __restrict__ centb)
{
    const int k = blockIdx.x;
    const int t = threadIdx.x;      // 512
    const int d = t & (DD - 1);
    const int slice = t >> 7;
    float s = 0.f;
    for (int b = slice; b < nparts; b += 4)
        s += partial[((size_t)b * KK + k) * DD + d];
    __shared__ float red[4][DD];
    red[slice][d] = s;
    __syncthreads();
    float v = 0.f;
    if (t < DD) v = red[0][d] + red[1][d] + red[2][d] + red[3][d];
    float sq = v * v;
#pragma unroll
    for (int m = 32; m > 0; m >>= 1) sq += __shfl_xor(sq, m);
    __shared__ float wsum[8];
    if ((t & 63) == 0) wsum[t >> 6] = sq;
    __syncthreads();
    if (t < DD) centb[k * DD + d] = f2bf(v * rsqrtf(wsum[0] + wsum[1]));
}

// ---------------- stage 3 (R4): X direct global->reg, barrier-free K loop ----------------
// A-rows are wave-private (no cross-wave X reuse), so X never needs LDS.
// Only C (256x128 bf16) stays in LDS, staged once.  Ping-pong register pairs
// keep one 32B/lane load in flight under each 16-MFMA burst; waves free-run.

static __device__ __forceinline__ short8 cvt_pair(const f32x4 lo, const f32x4 hi, float& x2p) {
    short8 r;
    // summation order identical to the old staged kernel: j = 0..3 (lo) then 4..7 (hi)
#pragma unroll
    for (int j = 0; j < 4; ++j) {
        const unsigned short u = f2bf(lo[j]);
        r[j] = (short)u;
        const float e = bf2f(u);
        x2p = fmaf(e, e, x2p);
    }
#pragma unroll
    for (int j = 0; j < 4; ++j) {
        const unsigned short u = f2bf(hi[j]);
        r[4 + j] = (short)u;
        const float e = bf2f(u);
        x2p = fmaf(e, e, x2p);
    }
    return r;
}

static __device__ __forceinline__ void mfma_step(
    f32x4* acc, const short8 afrag, const unsigned short* Cl,
    const int m15, const int kq, const int s)
{
#pragma unroll
    for (int t = 0; t < 16; ++t) {
        const short8 bfrag = *(const short8*)(&Cl[((t << 4) + m15) * ROWB + (s << 5) + kq]);
        acc[t] = __builtin_amdgcn_mfma_f32_16x16x32_bf16(afrag, bfrag, acc[t], 0, 0, 0);
    }
}

__global__ __launch_bounds__(1024, 4) void k_stage3(
    const float* __restrict__ Xf, const int* __restrict__ labels,
    const unsigned short* __restrict__ centb,
    const float* __restrict__ hbias, float* __restrict__ loss, int spb)
{
    __shared__ unsigned short Cl[KK * ROWB];
    __shared__ float lred[32];

    const int tid = threadIdx.x;
    const float hb = *hbias;
    const float bias = (hb > 20.f) ? hb : log1pf(__expf(hb));
    const float pos_bias = bias;
    const float neg_bias = 9.f * bias + 0.05f;

    const uint4* csrc = (const uint4*)centb;
    for (int c = tid; c < KK * DD / 8; c += 1024) {
        const int row = c >> 4;
        const int col = (c & 15) << 3;
        *(uint4*)(&Cl[row * ROWB + col]) = csrc[c];
    }
    __syncthreads();                 // only barrier before the final reduction

    const int lane = tid & 63;
    const int wave = tid >> 6;       // 0..15
    const int m15  = lane & 15;
    const int q    = lane >> 4;      // 0..3
    const int kq   = q << 3;
    const int base = blockIdx.x * spb;
    float pos_acc = 0.f, neg_acc = 0.f;

    // lane reads row (wave*16 + m15) of each tile, float chunk [s*32+kq, +8)
    const float* xp = Xf + (size_t)(base + (wave << 4) + m15) * DD + kq;

    f32x4 pa0 = *(const f32x4*)(xp);        // tile 0, s=0 prefetch
    f32x4 pa1 = *(const f32x4*)(xp + 4);
    f32x4 pb0, pb1;

    for (int t0 = 0; t0 < spb; t0 += TS) {
        const float* xt = xp + (size_t)t0 * DD;
        f32x4 acc[16];
#pragma unroll
        for (int t = 0; t < 16; ++t) acc[t] = (f32x4){0.f, 0.f, 0.f, 0.f};
        float x2p = 0.f;
        short8 afrag;

        // s = 0: consume pa, prefetch s=1 into pb
        afrag = cvt_pair(pa0, pa1, x2p);
        pb0 = *(const f32x4*)(xt + 32);
        pb1 = *(const f32x4*)(xt + 36);
        mfma_step(acc, afrag, Cl, m15, kq, 0);
        // s = 1: consume pb, prefetch s=2 into pa
        afrag = cvt_pair(pb0, pb1, x2p);
        pa0 = *(const f32x4*)(xt + 64);
        pa1 = *(const f32x4*)(xt + 68);
        mfma_step(acc, afrag, Cl, m15, kq, 1);
        // s = 2: consume pa, prefetch s=3 into pb
        afrag = cvt_pair(pa0, pa1, x2p);
        pb0 = *(const f32x4*)(xt + 96);
        pb1 = *(const f32x4*)(xt + 100);
        mfma_step(acc, afrag, Cl, m15, kq, 2);
        // s = 3: consume pb, prefetch next tile's s=0 into pa
        afrag = cvt_pair(pb0, pb1, x2p);
        if (t0 + TS < spb) {
            const float* xn = xt + (size_t)TS * DD;
            pa0 = *(const f32x4*)(xn);
            pa1 = *(const f32x4*)(xn + 4);
        }
        mfma_step(acc, afrag, Cl, m15, kq, 3);

        x2p += __shfl_xor(x2p, 16);
        x2p += __shfl_xor(x2p, 32);

#pragma unroll
        for (int r = 0; r < 4; ++r) {
            const int ml = (wave << 4) + (q << 2) + r;
            const int l  = labels[base + t0 + ml];   // L1-broadcast, was LDS labs[]
            const float x2 = __shfl(x2p, (q << 2) + r, 16);
            float posd = -1e30f, negd = -1e30f;
#pragma unroll
            for (int t = 0; t < 16; ++t) {
                const int cl = (t << 4) + m15;
                const float v = acc[t][r];
                const bool isp = (cl == l);
                posd = isp ? v : posd;
                negd = isp ? negd : fmaxf(negd, v);
            }
#pragma unroll
            for (int m = 1; m < 16; m <<= 1) {
                posd = fmaxf(posd, __shfl_xor(posd, m));
                negd = fmaxf(negd, __shfl_xor(negd, m));
            }
            if (m15 == 0) {
                const float pd = x2 + 1.0f - 2.f * posd;
                const float nd = x2 + 1.0f - 2.f * negd;
                pos_acc += fmaxf(pd - pos_bias, 0.f);
                neg_acc += fmaxf(neg_bias - nd, 0.f);
            }
        }
    }

#pragma unroll
    for (int m = 32; m > 0; m >>= 1) {
        pos_acc += __shfl_xor(pos_acc, m);
        neg_acc += __shfl_xor(neg_acc, m);
    }
    if (lane == 0) { lred[wave] = pos_acc; lred[16 + wave] = neg_acc; }
    __syncthreads();
    if (tid == 0) {
        float p = 0.f, n = 0.f;
#pragma unroll
        for (int w = 0; w < 16; ++w) { p += lred[w]; n += lred[16 + w]; }
        atomicAdd(&loss[0], p);
        atomicAdd(&loss[1], n);
    }
}

__global__ void k_final(const float* __restrict__ loss, float* __restrict__ out, float invN)
{
    if (threadIdx.x == 0) {
        out[0] = 4.0f * loss[0] * invN;
        out[1] = loss[1] * invN;
    }
}

extern "C" void kernel_launch(void* const* d_in, const int* in_sizes, int n_in,
                              void* d_out, int out_size, void* d_ws, size_t ws_size,
                              hipStream_t stream)
{
    const float* X      = (const float*)d_in[0];
    // d_in[1] (scores) is dead in the reference forward — never read.
    const int*   labels = (const int*)d_in[2];
    const float* hbias  = (const float*)d_in[3];
    float* out = (float*)d_out;
    const int N = in_sizes[0] / DD;
    const int G = N / SPB1;                   // 256 blocks

    char* ws = (char*)d_ws;
    const size_t offC    = 256;
    const size_t offPart = offC + (size_t)KK * DD * 2;
    const size_t szPart  = (size_t)G * KK * DD * 4;    // 32 MiB

    float*          loss    = (float*)ws;
    unsigned short* centb   = (unsigned short*)(ws + offC);
    float*          partial = (float*)(ws + offPart);

    const int mode   = (ws_size >= offPart + szPart) ? 0 : 2;
    const int nparts = (mode == 2) ? 1 : G;

    hipMemsetAsync(loss, 0, 2 * sizeof(float), stream);
    if (mode == 2) hipMemsetAsync(partial, 0, (size_t)KK * DD * 4, stream);

    if (mode == 0) k_stage1_gather<0><<<G, 1024, 0, stream>>>(X, labels, partial);
    else           k_stage1_gather<2><<<G, 1024, 0, stream>>>(X, labels, partial);

    k_stage2<<<KK, 512, 0, stream>>>(partial, nparts, centb);

    k_stage3<<<G, 1024, 0, stream>>>(X, labels, centb, hbias, loss, N / G);

    k_final<<<1, 64, 0, stream>>>(loss, out, 1.0f / (float)N);
}

// Round 2
// 531.926 us; speedup vs baseline: 1.3262x; 1.3262x over previous
//
#include <hip/hip_runtime.h>
#include <hip/hip_bf16.h>

#define DD 128
#define KK 256
#define TS 256        // samples per stage-3 tile
#define ROWB 136      // padded LDS row stride (bf16 elems)
#define SPB1 1024     // samples per stage-1 block

typedef __attribute__((ext_vector_type(8))) short short8;
typedef __attribute__((ext_vector_type(4))) float f32x4;

static __device__ __forceinline__ unsigned short f2bf(float f) {
    unsigned int u = __float_as_uint(f);
    return (unsigned short)((u + 0x7fffu + ((u >> 16) & 1u)) >> 16);   // RNE
}
static __device__ __forceinline__ float bf2f(unsigned short h) {
    return __uint_as_float(((unsigned int)h) << 16);
}

// ---------------- stage 1: counting-sort gather, 8-deep load pipeline ----------------
// MODE 0: per-block partial slot.  MODE 2: global-atomic merge (tiny-ws fallback).
template<int MODE>
__global__ __launch_bounds__(1024) void k_stage1_gather(
    const float* __restrict__ X, const int* __restrict__ labels,
    float* __restrict__ partial)
{
    __shared__ int lab[SPB1];
    __shared__ int idx[SPB1];
    __shared__ int hist[KK];
    __shared__ int start[KK + 1];
    __shared__ int cursor[KK];

    const int tid  = threadIdx.x;
    const int lane = tid & 63;
    const int wave = tid >> 6;
    const int base = blockIdx.x * SPB1;

    if (tid < KK) hist[tid] = 0;
    __syncthreads();
    {
        const int l = labels[base + tid];
        lab[tid] = l;
        atomicAdd(&hist[l], 1);
    }
    __syncthreads();
    if (wave == 0) {                        // exclusive scan of 256 bins in one wave
        const int h0 = hist[4*lane], h1 = hist[4*lane+1];
        const int h2 = hist[4*lane+2], h3 = hist[4*lane+3];
        const int s = h0 + h1 + h2 + h3;
        int t = s;
#pragma unroll
        for (int d = 1; d < 64; d <<= 1) { const int u = __shfl_up(t, d); if (lane >= d) t += u; }
        const int e = t - s;
        start[4*lane]   = e;
        start[4*lane+1] = e + h0;
        start[4*lane+2] = e + h0 + h1;
        start[4*lane+3] = e + h0 + h1 + h2;
        if (lane == 63) start[KK] = t;
    }
    __syncthreads();
    if (tid < KK) cursor[tid] = start[tid];
    __syncthreads();
    {
        const int pos = atomicAdd(&cursor[lab[tid]], 1);
        idx[pos] = tid;
    }
    __syncthreads();

    // wave w owns contiguous clusters [16w, 16w+16); flat member walk, 8 loads in flight
    const int c1 = (wave << 4) + 16;
    int c = wave << 4;
    const int s0 = start[c], s1 = start[c1];
    const int cnt = s1 - s0;
    int nx = start[c + 1];                  // register-cached cluster boundary

    float2 pf[8];
#pragma unroll
    for (int j = 0; j < 8; ++j)
        if (j < cnt)
            pf[j] = *(const float2*)(X + (size_t)(base + idx[s0 + j]) * DD + 2 * lane);

    float2 acc = make_float2(0.f, 0.f);
    int i = 0;
    for (; i + 8 <= cnt; i += 8) {
#pragma unroll
        for (int j = 0; j < 8; ++j) {
            const float2 v = pf[j];
            if (i + j + 8 < cnt)
                pf[j] = *(const float2*)(X + (size_t)(base + idx[s0 + i + j + 8]) * DD + 2 * lane);
            while (s0 + i + j >= nx) {       // wave-uniform boundary flush
                if (MODE == 2) {
                    atomicAdd(&partial[(size_t)c * DD + 2*lane],     acc.x);
                    atomicAdd(&partial[(size_t)c * DD + 2*lane + 1], acc.y);
                } else {
                    *(float2*)(partial + ((size_t)blockIdx.x * KK + c) * DD + 2*lane) = acc;
                }
                acc = make_float2(0.f, 0.f); ++c; nx = start[c + 1];
            }
            acc.x += v.x; acc.y += v.y;
        }
    }
#pragma unroll
    for (int j = 0; j < 8; ++j) {                       // tail (<8 rows), pf[j] = row i+j
        if (i + j < cnt) {
            const float2 v = pf[j];
            while (s0 + i + j >= nx) {
                if (MODE == 2) {
                    atomicAdd(&partial[(size_t)c * DD + 2*lane],     acc.x);
                    atomicAdd(&partial[(size_t)c * DD + 2*lane + 1], acc.y);
                } else {
                    *(float2*)(partial + ((size_t)blockIdx.x * KK + c) * DD + 2*lane) = acc;
                }
                acc = make_float2(0.f, 0.f); ++c; nx = start[c + 1];
            }
            acc.x += v.x; acc.y += v.y;
        }
    }
    while (c < c1) {                                    // flush trailing (incl. empty) clusters
        if (MODE == 2) {
            atomicAdd(&partial[(size_t)c * DD + 2*lane],     acc.x);
            atomicAdd(&partial[(size_t)c * DD + 2*lane + 1], acc.y);
        } else {
            *(float2*)(partial + ((size_t)blockIdx.x * KK + c) * DD + 2*lane) = acc;
        }
        acc = make_float2(0.f, 0.f); ++c;
    }
}

// ---------------- stage 2: reduce partials, normalize (counts cancel), emit bf16 ----------------
__global__ void k_stage2(const float* __restrict__ partial, int nparts,
                         unsigned short* __restrict__ centb)
{
    const int k = blockIdx.x;
    const int t = threadIdx.x;      // 512
    const int d = t & (DD - 1);
    const int slice = t >> 7;
    float s = 0.f;
    for (int b = slice; b < nparts; b += 4)
        s += partial[((size_t)b * KK + k) * DD + d];
    __shared__ float red[4][DD];
    red[slice][d] = s;
    __syncthreads();
    float v = 0.f;
    if (t < DD) v = red[0][d] + red[1][d] + red[2][d] + red[3][d];
    float sq = v * v;
#pragma unroll
    for (int m = 32; m > 0; m >>= 1) sq += __shfl_xor(sq, m);
    __shared__ float wsum[8];
    if ((t & 63) == 0) wsum[t >> 6] = sq;
    __syncthreads();
    if (t < DD) centb[k * DD + d] = f2bf(v * rsqrtf(wsum[0] + wsum[1]));
}

// ---------------- stage 3 (R5): LDS-staged X (the LDS IS the transpose) + T14 async-stage ----------------
// R1 lesson: MFMA A-layout (lane=row) is transposed vs coalesced loads (lane=col);
// direct global->reg gather over-fetched HBM 4.8x. So X goes back through LDS.
// T14: next tile's X is loaded into registers DURING the current tile's compute;
// between the barriers only f2bf + ds_write remain. Global-load latency is off
// the serial path. Compute is s-outer/t-inner (same per-acc accumulation order
// as R0 -> bitwise-identical) to cut live VGPRs (afrag[4] -> afrag).
__global__ __launch_bounds__(1024, 4) void k_stage3(
    const float* __restrict__ Xf, const int* __restrict__ labels,
    const unsigned short* __restrict__ centb,
    const float* __restrict__ hbias, float* __restrict__ loss, int spb)
{
    __shared__ unsigned short Cl[KK * ROWB];
    __shared__ unsigned short Xl[TS * ROWB];
    __shared__ float lred[32];

    const int tid = threadIdx.x;
    const float hb = *hbias;
    const float bias = (hb > 20.f) ? hb : log1pf(__expf(hb));
    const float pos_bias = bias;
    const float neg_bias = 9.f * bias + 0.05f;

    const uint4* csrc = (const uint4*)centb;
    for (int c = tid; c < KK * DD / 8; c += 1024) {
        const int row = c >> 4;
        const int col = (c & 15) << 3;
        *(uint4*)(&Cl[row * ROWB + col]) = csrc[c];
    }

    const int lane = tid & 63;
    const int wave = tid >> 6;       // 0..15
    const int m15  = lane & 15;
    const int q    = lane >> 4;
    const int kq   = q << 3;
    const int base = blockIdx.x * spb;
    float pos_acc = 0.f, neg_acc = 0.f;

    // T14 prologue: tile 0's X slice into registers (8 x float4 = 32 VGPR, coalesced)
    float4 r[8];
    {
        const float4* xsrc = (const float4*)(Xf + (size_t)base * DD);
#pragma unroll
        for (int k = 0; k < 8; ++k)
            r[k] = xsrc[tid + (k << 10)];
    }

    for (int t0 = 0; t0 < spb; t0 += TS) {
        __syncthreads();                       // prev compute done; Xl writable
#pragma unroll
        for (int k = 0; k < 8; ++k) {          // f2bf + ds_write only (LDS-fast)
            const int c = tid + (k << 10);
            const int row = c >> 5;
            const int col = (c & 31) << 2;
            const float4 v = r[k];
            ushort4 pk = make_ushort4(f2bf(v.x), f2bf(v.y), f2bf(v.z), f2bf(v.w));
            *(ushort4*)(&Xl[row * ROWB + col]) = pk;
        }
        if (t0 + TS < spb) {                   // issue next tile's loads; they fly
            const float4* xn = (const float4*)(Xf + (size_t)(base + t0 + TS) * DD);
#pragma unroll
            for (int k = 0; k < 8; ++k)
                r[k] = xn[tid + (k << 10)];
        }
        __syncthreads();                       // Xl ready

        f32x4 acc[16];
#pragma unroll
        for (int t = 0; t < 16; ++t) acc[t] = (f32x4){0.f, 0.f, 0.f, 0.f};
        float x2p = 0.f;

        const int arow = (wave << 4) + m15;
#pragma unroll
        for (int s = 0; s < 4; ++s) {
            const short8 afrag = *(const short8*)(&Xl[arow * ROWB + (s << 5) + kq]);
#pragma unroll
            for (int j = 0; j < 8; ++j) {      // same order as R0: s ascending, j 0..7
                const float e = bf2f((unsigned short)afrag[j]);
                x2p = fmaf(e, e, x2p);
            }
#pragma unroll
            for (int t = 0; t < 16; ++t) {     // per-acc[t] s-order unchanged -> bitwise-identical
                const short8 bfrag = *(const short8*)(&Cl[((t << 4) + m15) * ROWB + (s << 5) + kq]);
                acc[t] = __builtin_amdgcn_mfma_f32_16x16x32_bf16(afrag, bfrag, acc[t], 0, 0, 0);
            }
        }

        x2p += __shfl_xor(x2p, 16);
        x2p += __shfl_xor(x2p, 32);

#pragma unroll
        for (int r4 = 0; r4 < 4; ++r4) {
            const int ml = (wave << 4) + (q << 2) + r4;
            const int l  = labels[base + t0 + ml];   // broadcast read, L1-hit
            const float x2 = __shfl(x2p, (q << 2) + r4, 16);
            float posd = -1e30f, negd = -1e30f;
#pragma unroll
            for (int t = 0; t < 16; ++t) {
                const int cl = (t << 4) + m15;
                const float v = acc[t][r4];
                const bool isp = (cl == l);
                posd = isp ? v : posd;
                negd = isp ? negd : fmaxf(negd, v);
            }
#pragma unroll
            for (int m = 1; m < 16; m <<= 1) {
                posd = fmaxf(posd, __shfl_xor(posd, m));
                negd = fmaxf(negd, __shfl_xor(negd, m));
            }
            if (m15 == 0) {
                const float pd = x2 + 1.0f - 2.f * posd;
                const float nd = x2 + 1.0f - 2.f * negd;
                pos_acc += fmaxf(pd - pos_bias, 0.f);
                neg_acc += fmaxf(neg_bias - nd, 0.f);
            }
        }
    }

#pragma unroll
    for (int m = 32; m > 0; m >>= 1) {
        pos_acc += __shfl_xor(pos_acc, m);
        neg_acc += __shfl_xor(neg_acc, m);
    }
    if (lane == 0) { lred[wave] = pos_acc; lred[16 + wave] = neg_acc; }
    __syncthreads();
    if (tid == 0) {
        float p = 0.f, n = 0.f;
#pragma unroll
        for (int w = 0; w < 16; ++w) { p += lred[w]; n += lred[16 + w]; }
        atomicAdd(&loss[0], p);
        atomicAdd(&loss[1], n);
    }
}

__global__ void k_final(const float* __restrict__ loss, float* __restrict__ out, float invN)
{
    if (threadIdx.x == 0) {
        out[0] = 4.0f * loss[0] * invN;
        out[1] = loss[1] * invN;
    }
}

extern "C" void kernel_launch(void* const* d_in, const int* in_sizes, int n_in,
                              void* d_out, int out_size, void* d_ws, size_t ws_size,
                              hipStream_t stream)
{
    const float* X      = (const float*)d_in[0];
    // d_in[1] (scores) is dead in the reference forward — never read.
    const int*   labels = (const int*)d_in[2];
    const float* hbias  = (const float*)d_in[3];
    float* out = (float*)d_out;
    const int N = in_sizes[0] / DD;
    const int G = N / SPB1;                   // 256 blocks

    char* ws = (char*)d_ws;
    const size_t offC    = 256;
    const size_t offPart = offC + (size_t)KK * DD * 2;
    const size_t szPart  = (size_t)G * KK * DD * 4;    // 32 MiB

    float*          loss    = (float*)ws;
    unsigned short* centb   = (unsigned short*)(ws + offC);
    float*          partial = (float*)(ws + offPart);

    const int mode   = (ws_size >= offPart + szPart) ? 0 : 2;
    const int nparts = (mode == 2) ? 1 : G;

    hipMemsetAsync(loss, 0, 2 * sizeof(float), stream);
    if (mode == 2) hipMemsetAsync(partial, 0, (size_t)KK * DD * 4, stream);

    if (mode == 0) k_stage1_gather<0><<<G, 1024, 0, stream>>>(X, labels, partial);
    else           k_stage1_gather<2><<<G, 1024, 0, stream>>>(X, labels, partial);

    k_stage2<<<KK, 512, 0, stream>>>(partial, nparts, centb);

    k_stage3<<<G, 1024, 0, stream>>>(X, labels, centb, hbias, loss, N / G);

    k_final<<<1, 64, 0, stream>>>(loss, out, 1.0f / (float)N);
}

// Round 3
// 530.144 us; speedup vs baseline: 1.3307x; 1.0034x over previous
//
#include <hip/hip_runtime.h>
#include <hip/hip_bf16.h>

#define DD 128
#define KK 256
#define TS 256        // samples per stage-3 tile
#define ROWB 136      // padded LDS row stride (bf16 elems)
#define SPB1 1024     // samples per stage-1 block

typedef __attribute__((ext_vector_type(8))) short short8;
typedef __attribute__((ext_vector_type(4))) float f32x4;

static __device__ __forceinline__ unsigned short f2bf(float f) {
    unsigned int u = __float_as_uint(f);
    return (unsigned short)((u + 0x7fffu + ((u >> 16) & 1u)) >> 16);   // RNE
}
static __device__ __forceinline__ float bf2f(unsigned short h) {
    return __uint_as_float(((unsigned int)h) << 16);
}
static __device__ __forceinline__ uint2 pack4(const float4 v) {
    uint2 r;
    r.x = (unsigned)f2bf(v.x) | ((unsigned)f2bf(v.y) << 16);   // same layout as ushort4{x,y,z,w}
    r.y = (unsigned)f2bf(v.z) | ((unsigned)f2bf(v.w) << 16);
    return r;
}

// ---------------- stage 1: counting-sort gather, 8-deep load pipeline ----------------
// MODE 0: per-block partial slot.  MODE 2: global-atomic merge (tiny-ws fallback).
template<int MODE>
__global__ __launch_bounds__(1024) void k_stage1_gather(
    const float* __restrict__ X, const int* __restrict__ labels,
    float* __restrict__ partial)
{
    __shared__ int lab[SPB1];
    __shared__ int idx[SPB1];
    __shared__ int hist[KK];
    __shared__ int start[KK + 1];
    __shared__ int cursor[KK];

    const int tid  = threadIdx.x;
    const int lane = tid & 63;
    const int wave = tid >> 6;
    const int base = blockIdx.x * SPB1;

    if (tid < KK) hist[tid] = 0;
    __syncthreads();
    {
        const int l = labels[base + tid];
        lab[tid] = l;
        atomicAdd(&hist[l], 1);
    }
    __syncthreads();
    if (wave == 0) {                        // exclusive scan of 256 bins in one wave
        const int h0 = hist[4*lane], h1 = hist[4*lane+1];
        const int h2 = hist[4*lane+2], h3 = hist[4*lane+3];
        const int s = h0 + h1 + h2 + h3;
        int t = s;
#pragma unroll
        for (int d = 1; d < 64; d <<= 1) { const int u = __shfl_up(t, d); if (lane >= d) t += u; }
        const int e = t - s;
        start[4*lane]   = e;
        start[4*lane+1] = e + h0;
        start[4*lane+2] = e + h0 + h1;
        start[4*lane+3] = e + h0 + h1 + h2;
        if (lane == 63) start[KK] = t;
    }
    __syncthreads();
    if (tid < KK) cursor[tid] = start[tid];
    __syncthreads();
    {
        const int pos = atomicAdd(&cursor[lab[tid]], 1);
        idx[pos] = tid;
    }
    __syncthreads();

    // wave w owns contiguous clusters [16w, 16w+16); flat member walk, 8 loads in flight
    const int c1 = (wave << 4) + 16;
    int c = wave << 4;
    const int s0 = start[c], s1 = start[c1];
    const int cnt = s1 - s0;
    int nx = start[c + 1];                  // register-cached cluster boundary

    float2 pf[8];
#pragma unroll
    for (int j = 0; j < 8; ++j)
        if (j < cnt)
            pf[j] = *(const float2*)(X + (size_t)(base + idx[s0 + j]) * DD + 2 * lane);

    float2 acc = make_float2(0.f, 0.f);
    int i = 0;
    for (; i + 8 <= cnt; i += 8) {
#pragma unroll
        for (int j = 0; j < 8; ++j) {
            const float2 v = pf[j];
            if (i + j + 8 < cnt)
                pf[j] = *(const float2*)(X + (size_t)(base + idx[s0 + i + j + 8]) * DD + 2 * lane);
            while (s0 + i + j >= nx) {       // wave-uniform boundary flush
                if (MODE == 2) {
                    atomicAdd(&partial[(size_t)c * DD + 2*lane],     acc.x);
                    atomicAdd(&partial[(size_t)c * DD + 2*lane + 1], acc.y);
                } else {
                    *(float2*)(partial + ((size_t)blockIdx.x * KK + c) * DD + 2*lane) = acc;
                }
                acc = make_float2(0.f, 0.f); ++c; nx = start[c + 1];
            }
            acc.x += v.x; acc.y += v.y;
        }
    }
#pragma unroll
    for (int j = 0; j < 8; ++j) {                       // tail (<8 rows), pf[j] = row i+j
        if (i + j < cnt) {
            const float2 v = pf[j];
            while (s0 + i + j >= nx) {
                if (MODE == 2) {
                    atomicAdd(&partial[(size_t)c * DD + 2*lane],     acc.x);
                    atomicAdd(&partial[(size_t)c * DD + 2*lane + 1], acc.y);
                } else {
                    *(float2*)(partial + ((size_t)blockIdx.x * KK + c) * DD + 2*lane) = acc;
                }
                acc = make_float2(0.f, 0.f); ++c; nx = start[c + 1];
            }
            acc.x += v.x; acc.y += v.y;
        }
    }
    while (c < c1) {                                    // flush trailing (incl. empty) clusters
        if (MODE == 2) {
            atomicAdd(&partial[(size_t)c * DD + 2*lane],     acc.x);
            atomicAdd(&partial[(size_t)c * DD + 2*lane + 1], acc.y);
        } else {
            *(float2*)(partial + ((size_t)blockIdx.x * KK + c) * DD + 2*lane) = acc;
        }
        acc = make_float2(0.f, 0.f); ++c;
    }
}

// ---------------- stage 2: reduce partials, normalize (counts cancel), emit bf16 ----------------
__global__ void k_stage2(const float* __restrict__ partial, int nparts,
                         unsigned short* __restrict__ centb)
{
    const int k = blockIdx.x;
    const int t = threadIdx.x;      // 512
    const int d = t & (DD - 1);
    const int slice = t >> 7;
    float s = 0.f;
    for (int b = slice; b < nparts; b += 4)
        s += partial[((size_t)b * KK + k) * DD + d];
    __shared__ float red[4][DD];
    red[slice][d] = s;
    __syncthreads();
    float v = 0.f;
    if (t < DD) v = red[0][d] + red[1][d] + red[2][d] + red[3][d];
    float sq = v * v;
#pragma unroll
    for (int m = 32; m > 0; m >>= 1) sq += __shfl_xor(sq, m);
    __shared__ float wsum[8];
    if ((t & 63) == 0) wsum[t >> 6] = sq;
    __syncthreads();
    if (t < DD) centb[k * DD + d] = f2bf(v * rsqrtf(wsum[0] + wsum[1]));
}

// ---------------- stage 3 (R7): LDS-staged X, corrected T14 ----------------
// R2 lessons: (a) hipcc drains vmcnt(0) at every __syncthreads -> staging loads
// must be issued AFTER the last barrier of the tile, never before one;
// (b) keep the cross-phase staging state as packed bf16 (16 VGPRs), not f32 (32).
// Schedule per tile:  barrier -> 8x ds_write_b64(rp) -> barrier ->
//   issue 8 global float4 loads -> s0,s1 MFMA -> pack loads into rp -> s2,s3 -> epilogue.
// Loads get ~1600 cycles of cover (> ~900 cy HBM latency); their drain folds into
// the next tile's first barrier, which no longer has naked latency behind it.
__global__ __launch_bounds__(1024, 4) void k_stage3(
    const float* __restrict__ Xf, const int* __restrict__ labels,
    const unsigned short* __restrict__ centb,
    const float* __restrict__ hbias, float* __restrict__ loss, int spb)
{
    __shared__ unsigned short Cl[KK * ROWB];
    __shared__ unsigned short Xl[TS * ROWB];
    __shared__ float lred[32];

    const int tid = threadIdx.x;
    const float hb = *hbias;
    const float bias = (hb > 20.f) ? hb : log1pf(__expf(hb));
    const float pos_bias = bias;
    const float neg_bias = 9.f * bias + 0.05f;

    const uint4* csrc = (const uint4*)centb;
    for (int c = tid; c < KK * DD / 8; c += 1024) {
        const int row = c >> 4;
        const int col = (c & 15) << 3;
        *(uint4*)(&Cl[row * ROWB + col]) = csrc[c];
    }

    const int lane = tid & 63;
    const int wave = tid >> 6;       // 0..15
    const int m15  = lane & 15;
    const int q    = lane >> 4;
    const int kq   = q << 3;
    const int base = blockIdx.x * spb;
    float pos_acc = 0.f, neg_acc = 0.f;

    // tile-0 prefetch: load + pack to bf16 now (one exposed latency, prologue only)
    uint2 rp[8];
    {
        const float4* xsrc = (const float4*)(Xf + (size_t)base * DD);
#pragma unroll
        for (int k = 0; k < 8; ++k)
            rp[k] = pack4(xsrc[tid + (k << 10)]);
    }

    for (int t0 = 0; t0 < spb; t0 += TS) {
        __syncthreads();                       // Xl writable (also orders Cl on iter 0)
#pragma unroll
        for (int k = 0; k < 8; ++k) {          // inter-barrier region: 8 ds_write_b64 only
            const int c = tid + (k << 10);
            const int row = c >> 5;
            const int col = (c & 31) << 2;     // bf16-elem offset, same layout as R0
            *(uint2*)(&Xl[row * ROWB + col]) = rp[k];
        }
        __syncthreads();                       // Xl ready

        // issue next tile's loads AFTER the barrier so nothing drains them early
        const bool more = (t0 + TS < spb);
        float4 nv[8];
        if (more) {
            const float4* xn = (const float4*)(Xf + (size_t)(base + t0 + TS) * DD);
#pragma unroll
            for (int k = 0; k < 8; ++k)
                nv[k] = xn[tid + (k << 10)];
        }

        f32x4 acc[16];
#pragma unroll
        for (int t = 0; t < 16; ++t) acc[t] = (f32x4){0.f, 0.f, 0.f, 0.f};
        float x2p = 0.f;
        const int arow = (wave << 4) + m15;

#pragma unroll
        for (int s = 0; s < 2; ++s) {          // K-slices 0,1 under the loads
            const short8 afrag = *(const short8*)(&Xl[arow * ROWB + (s << 5) + kq]);
#pragma unroll
            for (int j = 0; j < 8; ++j) {
                const float e = bf2f((unsigned short)afrag[j]);
                x2p = fmaf(e, e, x2p);
            }
#pragma unroll
            for (int t = 0; t < 16; ++t) {
                const short8 bfrag = *(const short8*)(&Cl[((t << 4) + m15) * ROWB + (s << 5) + kq]);
                acc[t] = __builtin_amdgcn_mfma_f32_16x16x32_bf16(afrag, bfrag, acc[t], 0, 0, 0);
            }
        }

        if (more) {                            // ~1600 cy after issue: pack, free the f32 regs
#pragma unroll
            for (int k = 0; k < 8; ++k)
                rp[k] = pack4(nv[k]);
        }

#pragma unroll
        for (int s = 2; s < 4; ++s) {          // K-slices 2,3
            const short8 afrag = *(const short8*)(&Xl[arow * ROWB + (s << 5) + kq]);
#pragma unroll
            for (int j = 0; j < 8; ++j) {
                const float e = bf2f((unsigned short)afrag[j]);
                x2p = fmaf(e, e, x2p);
            }
#pragma unroll
            for (int t = 0; t < 16; ++t) {
                const short8 bfrag = *(const short8*)(&Cl[((t << 4) + m15) * ROWB + (s << 5) + kq]);
                acc[t] = __builtin_amdgcn_mfma_f32_16x16x32_bf16(afrag, bfrag, acc[t], 0, 0, 0);
            }
        }

        x2p += __shfl_xor(x2p, 16);
        x2p += __shfl_xor(x2p, 32);

#pragma unroll
        for (int r4 = 0; r4 < 4; ++r4) {
            const int ml = (wave << 4) + (q << 2) + r4;
            const int l  = labels[base + t0 + ml];   // broadcast read, L1-hit
            const float x2 = __shfl(x2p, (q << 2) + r4, 16);
            float posd = -1e30f, negd = -1e30f;
#pragma unroll
            for (int t = 0; t < 16; ++t) {
                const int cl = (t << 4) + m15;
                const float v = acc[t][r4];
                const bool isp = (cl == l);
                posd = isp ? v : posd;
                negd = isp ? negd : fmaxf(negd, v);
            }
#pragma unroll
            for (int m = 1; m < 16; m <<= 1) {
                posd = fmaxf(posd, __shfl_xor(posd, m));
                negd = fmaxf(negd, __shfl_xor(negd, m));
            }
            if (m15 == 0) {
                const float pd = x2 + 1.0f - 2.f * posd;
                const float nd = x2 + 1.0f - 2.f * negd;
                pos_acc += fmaxf(pd - pos_bias, 0.f);
                neg_acc += fmaxf(neg_bias - nd, 0.f);
            }
        }
    }

#pragma unroll
    for (int m = 32; m > 0; m >>= 1) {
        pos_acc += __shfl_xor(pos_acc, m);
        neg_acc += __shfl_xor(neg_acc, m);
    }
    if (lane == 0) { lred[wave] = pos_acc; lred[16 + wave] = neg_acc; }
    __syncthreads();
    if (tid == 0) {
        float p = 0.f, n = 0.f;
#pragma unroll
        for (int w = 0; w < 16; ++w) { p += lred[w]; n += lred[16 + w]; }
        atomicAdd(&loss[0], p);
        atomicAdd(&loss[1], n);
    }
}

__global__ void k_final(const float* __restrict__ loss, float* __restrict__ out, float invN)
{
    if (threadIdx.x == 0) {
        out[0] = 4.0f * loss[0] * invN;
        out[1] = loss[1] * invN;
    }
}

extern "C" void kernel_launch(void* const* d_in, const int* in_sizes, int n_in,
                              void* d_out, int out_size, void* d_ws, size_t ws_size,
                              hipStream_t stream)
{
    const float* X      = (const float*)d_in[0];
    // d_in[1] (scores) is dead in the reference forward — never read.
    const int*   labels = (const int*)d_in[2];
    const float* hbias  = (const float*)d_in[3];
    float* out = (float*)d_out;
    const int N = in_sizes[0] / DD;
    const int G = N / SPB1;                   // 256 blocks

    char* ws = (char*)d_ws;
    const size_t offC    = 256;
    const size_t offPart = offC + (size_t)KK * DD * 2;
    const size_t szPart  = (size_t)G * KK * DD * 4;    // 32 MiB

    float*          loss    = (float*)ws;
    unsigned short* centb   = (unsigned short*)(ws + offC);
    float*          partial = (float*)(ws + offPart);

    const int mode   = (ws_size >= offPart + szPart) ? 0 : 2;
    const int nparts = (mode == 2) ? 1 : G;

    hipMemsetAsync(loss, 0, 2 * sizeof(float), stream);
    if (mode == 2) hipMemsetAsync(partial, 0, (size_t)KK * DD * 4, stream);

    if (mode == 0) k_stage1_gather<0><<<G, 1024, 0, stream>>>(X, labels, partial);
    else           k_stage1_gather<2><<<G, 1024, 0, stream>>>(X, labels, partial);

    k_stage2<<<KK, 512, 0, stream>>>(partial, nparts, centb);

    k_stage3<<<G, 1024, 0, stream>>>(X, labels, centb, hbias, loss, N / G);

    k_final<<<1, 64, 0, stream>>>(loss, out, 1.0f / (float)N);
}